// Round 3
// baseline (446.137 us; speedup 1.0000x reference)
//
#include <hip/hip_runtime.h>
#include <hip/hip_bf16.h>
#include <cstdint>

#define Bdim 4
#define Ldim 4096
#define Hdim 16
#define Cdim 64
#define Rdim 256
#define HCdim 1024

typedef __attribute__((ext_vector_type(8))) __bf16 bf16x8;
typedef __attribute__((ext_vector_type(4))) float f32x4;

union ABFrag { short4 s4[2]; int4 i4; bf16x8 v; };

__device__ __forceinline__ unsigned short f2b(float f) {
    union { float f; uint32_t u; } x; x.f = f;
    uint32_t r = x.u + 0x7FFFu + ((x.u >> 16) & 1u);
    return (unsigned short)(r >> 16);
}
__device__ __forceinline__ float b2f(unsigned short h) {
    union { float f; uint32_t u; } x; x.u = ((uint32_t)h) << 16; return x.f;
}

// ---------------- Kernel A: K/V projections ----------------
// out[b][r][hc] = sum_l proj[l][r] * X[b][l][hc]
// sel=0: K -> wk as [b][h][r][c] bf16 ; sel=1: V -> wv as [b][h][c][r] bf16
#define A_BM 64
#define A_BN 128
#define A_BK 64
#define A_SA 72   // LDS row stride (shorts): 64+8 pad, 144B = 16B-aligned rows

__global__ __launch_bounds__(512, 2)
void proj_kernel(const float* __restrict__ kin, const float* __restrict__ vin,
                 const float* __restrict__ pk,  const float* __restrict__ pv,
                 unsigned short* __restrict__ wk, unsigned short* __restrict__ wv)
{
    __shared__ unsigned short lds[(A_BM + A_BN) * A_SA];
    unsigned short* la = lds;                 // [64 r][72]
    unsigned short* lb = lds + A_BM * A_SA;   // [128 n][72]

    const int sel = blockIdx.z;
    const int b   = blockIdx.y;
    const int mt  = blockIdx.x & 3;           // 4 r-tiles
    const int nt  = blockIdx.x >> 2;          // 8 n-tiles
    const int r0  = mt * A_BM;
    const int n0  = nt * A_BN;

    const float* proj = sel ? pv : pk;
    const float* X    = (sel ? vin : kin) + (size_t)b * Ldim * HCdim;

    const int t    = threadIdx.x;
    const int lane = t & 63;
    const int w    = t >> 6;          // 0..7
    const int wm   = w >> 2;          // 0..1 (32 rows each)
    const int wn   = w & 3;           // 0..3 (32 cols each)
    const int g    = lane >> 4;       // 0..3
    const int ln15 = lane & 15;

    f32x4 acc[2][2] = {};

    const int a_rr4 = (t & 15) * 4, a_kk = t >> 4;   // A: 2 passes
    const int b_nn4 = (t & 31) * 4, b_kk = t >> 5;   // B: 4 passes

    for (int l0 = 0; l0 < Ldim; l0 += A_BK) {
        // stage A (proj): 64 r x 64 k, transpose fp32->bf16
        #pragma unroll
        for (int p = 0; p < 2; ++p) {
            int kk = a_kk + p * 32;
            float4 vA = *(const float4*)(proj + (size_t)(l0 + kk) * Rdim + (r0 + a_rr4));
            la[(a_rr4 + 0) * A_SA + kk] = f2b(vA.x);
            la[(a_rr4 + 1) * A_SA + kk] = f2b(vA.y);
            la[(a_rr4 + 2) * A_SA + kk] = f2b(vA.z);
            la[(a_rr4 + 3) * A_SA + kk] = f2b(vA.w);
        }
        // stage B (X): 128 n x 64 k, transpose fp32->bf16
        #pragma unroll
        for (int p = 0; p < 4; ++p) {
            int kk = b_kk + p * 16;
            float4 vB = *(const float4*)(X + (size_t)(l0 + kk) * HCdim + (n0 + b_nn4));
            lb[(b_nn4 + 0) * A_SA + kk] = f2b(vB.x);
            lb[(b_nn4 + 1) * A_SA + kk] = f2b(vB.y);
            lb[(b_nn4 + 2) * A_SA + kk] = f2b(vB.z);
            lb[(b_nn4 + 3) * A_SA + kk] = f2b(vB.w);
        }
        __syncthreads();

        ABFrag af[2][2], bfr[2][2];
        #pragma unroll
        for (int mf = 0; mf < 2; ++mf)
            #pragma unroll
            for (int ks = 0; ks < 2; ++ks)
                af[mf][ks].i4 = *(const int4*)&la[(wm*32 + mf*16 + ln15) * A_SA + ks*32 + 8*g];
        #pragma unroll
        for (int nf = 0; nf < 2; ++nf)
            #pragma unroll
            for (int ks = 0; ks < 2; ++ks)
                bfr[nf][ks].i4 = *(const int4*)&lb[(wn*32 + nf*16 + ln15) * A_SA + ks*32 + 8*g];
        #pragma unroll
        for (int mf = 0; mf < 2; ++mf)
            #pragma unroll
            for (int nf = 0; nf < 2; ++nf)
                #pragma unroll
                for (int ks = 0; ks < 2; ++ks)
                    acc[mf][nf] = __builtin_amdgcn_mfma_f32_16x16x32_bf16(
                        af[mf][ks].v, bfr[nf][ks].v, acc[mf][nf], 0, 0, 0);
        __syncthreads();
    }

    #pragma unroll
    for (int mf = 0; mf < 2; ++mf) {
        #pragma unroll
        for (int nf = 0; nf < 2; ++nf) {
            #pragma unroll
            for (int j = 0; j < 4; ++j) {
                int r  = r0 + wm*32 + mf*16 + 4*g + j;
                int hc = n0 + wn*32 + nf*16 + ln15;
                int h = hc >> 6, c = hc & 63;
                unsigned short val = f2b(acc[mf][nf][j]);
                if (sel == 0)
                    wk[(((size_t)b*Hdim + h)*Rdim + r)*Cdim + c] = val;   // [b][h][r][c]
                else
                    wv[(((size_t)b*Hdim + h)*Cdim + c)*Rdim + r] = val;   // [b][h][c][r]
            }
        }
    }
}

// ---------------- Kernel B: attention against R=256 slots ----------------
#define B_SQK 72   // q/kp LDS row stride (shorts), 144B rows (16B aligned)
#define B_SVR 264  // p LDS row stride (shorts), 528B rows (16B aligned)

__global__ __launch_bounds__(256, 3)
void attn_kernel(const float* __restrict__ q,
                 const unsigned short* __restrict__ wk,
                 const unsigned short* __restrict__ wv,
                 float* __restrict__ out)
{
    __shared__ unsigned short lds[23040];      // 46080 B
    unsigned short* q_lds  = lds;              // [64][72]
    unsigned short* kp_lds = lds + 64*B_SQK;   // [256][72]
    unsigned short* p_lds  = lds;              // overlay after S: [64][264]

    const int l0 = blockIdx.x * 64;
    const int bh = blockIdx.y;
    const int b = bh >> 4, h = bh & 15;

    const int t = threadIdx.x;
    const int lane = t & 63;
    const int w = t >> 6;            // wave 0..3 -> rows w*16..w*16+15
    const int g = lane >> 4;
    const int ln15 = lane & 15;

    // stage Q tile (fp32 -> bf16), rows l0..l0+63
    {
        const int ll = t >> 4, c4 = (t & 15) * 4;
        #pragma unroll
        for (int p = 0; p < 4; ++p) {
            int row = ll + p * 16;
            float4 v = *(const float4*)(q + (((size_t)b*Ldim + l0 + row)*Hdim + h)*Cdim + c4);
            short4 s;
            s.x = (short)f2b(v.x); s.y = (short)f2b(v.y);
            s.z = (short)f2b(v.z); s.w = (short)f2b(v.w);
            *(short4*)&q_lds[row*B_SQK + c4] = s;
        }
    }
    // stage Kp (bf16 copy) [256][64]
    {
        const int c8 = (t & 7) * 8, r = t >> 3;
        #pragma unroll
        for (int p = 0; p < 8; ++p) {
            int row = r + p * 32;
            *(int4*)&kp_lds[row*B_SQK + c8] =
                *(const int4*)&wk[((size_t)bh*Rdim + row)*Cdim + c8];
        }
    }
    __syncthreads();

    // S = Q Kp^T  (per wave: 16 rows x 256 r)
    ABFrag qa[2];
    #pragma unroll
    for (int ks = 0; ks < 2; ++ks)
        qa[ks].i4 = *(const int4*)&q_lds[(w*16 + ln15)*B_SQK + ks*32 + 8*g];

    f32x4 sacc[16] = {};
    #pragma unroll
    for (int rf = 0; rf < 16; ++rf) {
        #pragma unroll
        for (int ks = 0; ks < 2; ++ks) {
            ABFrag kb;
            kb.i4 = *(const int4*)&kp_lds[(rf*16 + ln15)*B_SQK + ks*32 + 8*g];
            sacc[rf] = __builtin_amdgcn_mfma_f32_16x16x32_bf16(qa[ks].v, kb.v, sacc[rf], 0,0,0);
        }
    }
    __syncthreads();   // all waves done reading q_lds/kp_lds before P overlay

    // softmax over r for rows m = 4g+j; scale = 1/8 folded into exp
    float mx[4] = {-1e30f,-1e30f,-1e30f,-1e30f};
    #pragma unroll
    for (int rf = 0; rf < 16; ++rf)
        #pragma unroll
        for (int j = 0; j < 4; ++j)
            mx[j] = fmaxf(mx[j], sacc[rf][j]);
    #pragma unroll
    for (int j = 0; j < 4; ++j) {
        mx[j] = fmaxf(mx[j], __shfl_xor(mx[j], 1));
        mx[j] = fmaxf(mx[j], __shfl_xor(mx[j], 2));
        mx[j] = fmaxf(mx[j], __shfl_xor(mx[j], 4));
        mx[j] = fmaxf(mx[j], __shfl_xor(mx[j], 8));
    }
    float sum[4] = {0,0,0,0};
    #pragma unroll
    for (int rf = 0; rf < 16; ++rf) {
        #pragma unroll
        for (int j = 0; j < 4; ++j) {
            float e = __expf((sacc[rf][j] - mx[j]) * 0.125f);
            unsigned short pb = f2b(e);
            sum[j] += b2f(pb);   // denominator matches bf16-rounded numerator
            p_lds[(w*16 + 4*g + j)*B_SVR + rf*16 + ln15] = pb;
        }
    }
    float rs[4];
    #pragma unroll
    for (int j = 0; j < 4; ++j) {
        sum[j] += __shfl_xor(sum[j], 1);
        sum[j] += __shfl_xor(sum[j], 2);
        sum[j] += __shfl_xor(sum[j], 4);
        sum[j] += __shfl_xor(sum[j], 8);
        rs[j] = 1.0f / sum[j];
    }
    // no barrier needed: each wave reads only its own P rows (program order within wave)

    // O = P Vp ; Vp fragments direct from global (L2-resident, [b][h][c][r] layout)
    const unsigned short* vb_base = wv + (size_t)bh * Cdim * Rdim;
    f32x4 oacc[4] = {};
    #pragma unroll
    for (int ks = 0; ks < 8; ++ks) {
        ABFrag pa;
        pa.i4 = *(const int4*)&p_lds[(w*16 + ln15)*B_SVR + ks*32 + 8*g];
        #pragma unroll
        for (int nf = 0; nf < 4; ++nf) {
            ABFrag vbf;
            vbf.i4 = *(const int4*)(vb_base + ((size_t)(nf*16 + ln15))*Rdim + ks*32 + 8*g);
            oacc[nf] = __builtin_amdgcn_mfma_f32_16x16x32_bf16(pa.v, vbf.v, oacc[nf], 0,0,0);
        }
    }

    #pragma unroll
    for (int nf = 0; nf < 4; ++nf)
        #pragma unroll
        for (int j = 0; j < 4; ++j)
            out[(((size_t)b*Ldim + l0 + w*16 + 4*g + j)*Hdim + h)*Cdim + nf*16 + ln15]
                = oacc[nf][j] * rs[j];
}

extern "C" void kernel_launch(void* const* d_in, const int* in_sizes, int n_in,
                              void* d_out, int out_size, void* d_ws, size_t ws_size,
                              hipStream_t stream)
{
    const float* q  = (const float*)d_in[0];
    const float* k  = (const float*)d_in[1];
    const float* v  = (const float*)d_in[2];
    const float* pk = (const float*)d_in[3];
    const float* pv = (const float*)d_in[4];
    float* out = (float*)d_out;

    unsigned short* wk = (unsigned short*)d_ws;                       // [B][H][R][C] bf16
    unsigned short* wv = wk + (size_t)Bdim*Hdim*Rdim*Cdim;            // [B][H][C][R] bf16

    proj_kernel<<<dim3(32, Bdim, 2), 512, 0, stream>>>(k, v, pk, pv, wk, wv);
    attn_kernel<<<dim3(Ldim/64, Bdim*Hdim), 256, 0, stream>>>(q, wk, wv, out);
}

// Round 6
// 341.581 us; speedup vs baseline: 1.3061x; 1.3061x over previous
//
#include <hip/hip_runtime.h>
#include <hip/hip_bf16.h>
#include <cstdint>

#define Bdim 4
#define Ldim 4096
#define Hdim 16
#define Cdim 64
#define Rdim 256
#define HCdim 1024

typedef __attribute__((ext_vector_type(8))) __bf16 bf16x8;
typedef __attribute__((ext_vector_type(4))) float f32x4;

union ABFrag { short4 s4[2]; int4 i4; bf16x8 v; };

__device__ __forceinline__ unsigned short f2b(float f) {
    union { float f; uint32_t u; } x; x.f = f;
    uint32_t r = x.u + 0x7FFFu + ((x.u >> 16) & 1u);
    return (unsigned short)(r >> 16);
}
__device__ __forceinline__ float b2f(unsigned short h) {
    union { float f; uint32_t u; } x; x.u = ((uint32_t)h) << 16; return x.f;
}
// pack two fp32 -> one u32 of 2 bf16 (low = a, high = b) via v_cvt_pk_bf16_f32
__device__ __forceinline__ uint32_t pack_bf2(float a, float b) {
    __hip_bfloat162 h = __float22bfloat162_rn(make_float2(a, b));
    union { __hip_bfloat162 h; uint32_t u; } c; c.h = h; return c.u;
}

// ---------------- Kernel A: K/V projections ----------------
// out[b][r][hc] = sum_l proj[l][r] * X[b][l][hc]
// sel=0: K -> wk as [b][h][r][c] bf16 ; sel=1: V -> wv as [b][h][c][r] bf16
//
// v3: 64x64 tiles, 256 threads, 512 blocks (2/CU).
// LDS tiles as u32 k-pairs: row m, col kp=k/2 in [0,32), row stride 36 u32.
// XOR swizzle on col bits 2..4 with sw(m) = (m>>3)&7:
//   write (ds_write_b32, rows m=4i+j, shared kp): sw=(i>>1)&7 pairs opposite
//   i-parities -> bank residues (d+4(i&1)) mod 8 uniform -> 2-way = free.
//   read (ds_read_b128, 16 consecutive m): halves cover all 8 bank-quads -> 2-way.
// Bijective on [0,32) per row; read uses same function -> correctness-neutral.
#define A_BK 64
#define A_S32 36   // u32 row stride (32 data + 4 pad)

__device__ __forceinline__ int swz_col(int m, int col) {
    return col ^ (((m >> 3) & 7) << 2);
}

__global__ __launch_bounds__(256, 2)
void proj_kernel(const float* __restrict__ kin, const float* __restrict__ vin,
                 const float* __restrict__ pk,  const float* __restrict__ pv,
                 unsigned short* __restrict__ wk, unsigned short* __restrict__ wv)
{
    __shared__ uint32_t lds32[128 * A_S32];          // 18432 B
    uint32_t* la = lds32;                            // A: [64 m(r)][36]
    uint32_t* lb = lds32 + 64 * A_S32;               // B: [64 n(hc)][36]

    // XCD-chunked bijective swizzle (512 % 8 == 0)
    const int o   = (blockIdx.x & 7) * 64 + (blockIdx.x >> 3);
    const int nt  = o & 15;
    const int mt  = (o >> 4) & 3;
    const int b   = (o >> 6) & 3;
    const int sel = o >> 8;
    const int r0  = mt * 64;
    const int n0  = nt * 64;

    const float* proj = sel ? pv : pk;
    const float* X    = (sel ? vin : kin) + (size_t)b * Ldim * HCdim;

    const int t    = threadIdx.x;          // 0..255
    const int lane = t & 63;
    const int w    = t >> 6;               // 0..3
    const int wm   = w >> 1;               // 0..1 (32 m-rows)
    const int wn   = w & 1;                // 0..1 (32 n-rows)
    const int g    = lane >> 4;            // 0..3
    const int ln15 = lane & 15;

    f32x4 acc[2][2] = {};

    for (int l0 = 0; l0 < Ldim; l0 += A_BK) {
        // ---- stage A (proj slab, 64 r x 64 l) and B (X slab, 64 hc x 64 l) ----
        // unit u = t + 256*p : m4 = (u&15)*4, kp = u>>4 (k = 2kp, 2kp+1)
        #pragma unroll
        for (int p = 0; p < 2; ++p) {
            const int u  = t + 256 * p;
            const int m4 = (u & 15) * 4;
            const int kp = u >> 4;
            const int l  = l0 + 2 * kp;
            float4 a0 = *(const float4*)(proj + (size_t)l * Rdim + r0 + m4);
            float4 a1 = *(const float4*)(proj + (size_t)(l + 1) * Rdim + r0 + m4);
            float4 b0 = *(const float4*)(X + (size_t)l * HCdim + n0 + m4);
            float4 b1 = *(const float4*)(X + (size_t)(l + 1) * HCdim + n0 + m4);
            const float* a0f = &a0.x; const float* a1f = &a1.x;
            const float* b0f = &b0.x; const float* b1f = &b1.x;
            #pragma unroll
            for (int j = 0; j < 4; ++j) {
                int m = m4 + j;
                la[m * A_S32 + swz_col(m, kp)] = pack_bf2(a0f[j], a1f[j]);
                lb[m * A_S32 + swz_col(m, kp)] = pack_bf2(b0f[j], b1f[j]);
            }
        }
        __syncthreads();

        // ---- fragments + MFMA ----
        ABFrag af[2][2], bfr[2][2];
        #pragma unroll
        for (int mf = 0; mf < 2; ++mf) {
            int m = wm * 32 + mf * 16 + ln15;
            #pragma unroll
            for (int ks = 0; ks < 2; ++ks)
                af[mf][ks].i4 = *(const int4*)&la[m * A_S32 + swz_col(m, ks * 16 + 4 * g)];
        }
        #pragma unroll
        for (int nf = 0; nf < 2; ++nf) {
            int n = wn * 32 + nf * 16 + ln15;
            #pragma unroll
            for (int ks = 0; ks < 2; ++ks)
                bfr[nf][ks].i4 = *(const int4*)&lb[n * A_S32 + swz_col(n, ks * 16 + 4 * g)];
        }
        #pragma unroll
        for (int mf = 0; mf < 2; ++mf)
            #pragma unroll
            for (int nf = 0; nf < 2; ++nf)
                #pragma unroll
                for (int ks = 0; ks < 2; ++ks)
                    acc[mf][nf] = __builtin_amdgcn_mfma_f32_16x16x32_bf16(
                        af[mf][ks].v, bfr[nf][ks].v, acc[mf][nf], 0, 0, 0);
        __syncthreads();
    }

    #pragma unroll
    for (int mf = 0; mf < 2; ++mf) {
        #pragma unroll
        for (int nf = 0; nf < 2; ++nf) {
            #pragma unroll
            for (int j = 0; j < 4; ++j) {
                int r  = r0 + wm * 32 + mf * 16 + 4 * g + j;
                int hc = n0 + wn * 32 + nf * 16 + ln15;
                int h = hc >> 6, c = hc & 63;
                unsigned short val = f2b(acc[mf][nf][j]);
                if (sel == 0)
                    wk[(((size_t)b * Hdim + h) * Rdim + r) * Cdim + c] = val;   // [b][h][r][c]
                else
                    wv[(((size_t)b * Hdim + h) * Cdim + c) * Rdim + r] = val;   // [b][h][c][r]
            }
        }
    }
}

// ---------------- Kernel B: attention against R=256 slots ----------------
#define B_SQK 72   // q/kp LDS row stride (shorts), 144B rows (16B aligned)
#define B_SVR 264  // p LDS row stride (shorts), 528B rows (16B aligned)

__global__ __launch_bounds__(256, 3)
void attn_kernel(const float* __restrict__ q,
                 const unsigned short* __restrict__ wk,
                 const unsigned short* __restrict__ wv,
                 float* __restrict__ out)
{
    __shared__ unsigned short lds[23040];      // 46080 B
    unsigned short* q_lds  = lds;              // [64][72]
    unsigned short* kp_lds = lds + 64*B_SQK;   // [256][72]
    unsigned short* p_lds  = lds;              // overlay after S: [64][264]

    const int l0 = blockIdx.x * 64;
    const int bh = blockIdx.y;
    const int b = bh >> 4, h = bh & 15;

    const int t = threadIdx.x;
    const int lane = t & 63;
    const int w = t >> 6;            // wave 0..3 -> rows w*16..w*16+15
    const int g = lane >> 4;
    const int ln15 = lane & 15;

    // stage Q tile (fp32 -> bf16), rows l0..l0+63
    {
        const int ll = t >> 4, c4 = (t & 15) * 4;
        #pragma unroll
        for (int p = 0; p < 4; ++p) {
            int row = ll + p * 16;
            float4 v = *(const float4*)(q + (((size_t)b*Ldim + l0 + row)*Hdim + h)*Cdim + c4);
            short4 s;
            s.x = (short)f2b(v.x); s.y = (short)f2b(v.y);
            s.z = (short)f2b(v.z); s.w = (short)f2b(v.w);
            *(short4*)&q_lds[row*B_SQK + c4] = s;
        }
    }
    // stage Kp (bf16 copy) [256][64]
    {
        const int c8 = (t & 7) * 8, r = t >> 3;
        #pragma unroll
        for (int p = 0; p < 8; ++p) {
            int row = r + p * 32;
            *(int4*)&kp_lds[row*B_SQK + c8] =
                *(const int4*)&wk[((size_t)bh*Rdim + row)*Cdim + c8];
        }
    }
    __syncthreads();

    // S = Q Kp^T  (per wave: 16 rows x 256 r)
    ABFrag qa[2];
    #pragma unroll
    for (int ks = 0; ks < 2; ++ks)
        qa[ks].i4 = *(const int4*)&q_lds[(w*16 + ln15)*B_SQK + ks*32 + 8*g];

    f32x4 sacc[16] = {};
    #pragma unroll
    for (int rf = 0; rf < 16; ++rf) {
        #pragma unroll
        for (int ks = 0; ks < 2; ++ks) {
            ABFrag kb;
            kb.i4 = *(const int4*)&kp_lds[(rf*16 + ln15)*B_SQK + ks*32 + 8*g];
            sacc[rf] = __builtin_amdgcn_mfma_f32_16x16x32_bf16(qa[ks].v, kb.v, sacc[rf], 0,0,0);
        }
    }
    __syncthreads();   // all waves done reading q_lds/kp_lds before P overlay

    // softmax over r for rows m = 4g+j; scale = 1/8 folded into exp
    float mx[4] = {-1e30f,-1e30f,-1e30f,-1e30f};
    #pragma unroll
    for (int rf = 0; rf < 16; ++rf)
        #pragma unroll
        for (int j = 0; j < 4; ++j)
            mx[j] = fmaxf(mx[j], sacc[rf][j]);
    #pragma unroll
    for (int j = 0; j < 4; ++j) {
        mx[j] = fmaxf(mx[j], __shfl_xor(mx[j], 1));
        mx[j] = fmaxf(mx[j], __shfl_xor(mx[j], 2));
        mx[j] = fmaxf(mx[j], __shfl_xor(mx[j], 4));
        mx[j] = fmaxf(mx[j], __shfl_xor(mx[j], 8));
    }
    float sum[4] = {0,0,0,0};
    #pragma unroll
    for (int rf = 0; rf < 16; ++rf) {
        #pragma unroll
        for (int j = 0; j < 4; ++j) {
            float e = __expf((sacc[rf][j] - mx[j]) * 0.125f);
            unsigned short pb = f2b(e);
            sum[j] += b2f(pb);   // denominator matches bf16-rounded numerator
            p_lds[(w*16 + 4*g + j)*B_SVR + rf*16 + ln15] = pb;
        }
    }
    float rs[4];
    #pragma unroll
    for (int j = 0; j < 4; ++j) {
        sum[j] += __shfl_xor(sum[j], 1);
        sum[j] += __shfl_xor(sum[j], 2);
        sum[j] += __shfl_xor(sum[j], 4);
        sum[j] += __shfl_xor(sum[j], 8);
        rs[j] = 1.0f / sum[j];
    }
    // no barrier needed: each wave reads only its own P rows (program order within wave)

    // O = P Vp ; Vp fragments direct from global (L2-resident, [b][h][c][r] layout)
    const unsigned short* vb_base = wv + (size_t)bh * Cdim * Rdim;
    f32x4 oacc[4] = {};
    #pragma unroll
    for (int ks = 0; ks < 8; ++ks) {
        ABFrag pa;
        pa.i4 = *(const int4*)&p_lds[(w*16 + ln15)*B_SVR + ks*32 + 8*g];
        #pragma unroll
        for (int nf = 0; nf < 4; ++nf) {
            ABFrag vbf;
            vbf.i4 = *(const int4*)(vb_base + ((size_t)(nf*16 + ln15))*Rdim + ks*32 + 8*g);
            oacc[nf] = __builtin_amdgcn_mfma_f32_16x16x32_bf16(pa.v, vbf.v, oacc[nf], 0,0,0);
        }
    }

    #pragma unroll
    for (int nf = 0; nf < 4; ++nf)
        #pragma unroll
        for (int j = 0; j < 4; ++j)
            out[(((size_t)b*Ldim + l0 + w*16 + 4*g + j)*Hdim + h)*Cdim + nf*16 + ln15]
                = oacc[nf][j] * rs[j];
}

extern "C" void kernel_launch(void* const* d_in, const int* in_sizes, int n_in,
                              void* d_out, int out_size, void* d_ws, size_t ws_size,
                              hipStream_t stream)
{
    const float* q  = (const float*)d_in[0];
    const float* k  = (const float*)d_in[1];
    const float* v  = (const float*)d_in[2];
    const float* pk = (const float*)d_in[3];
    const float* pv = (const float*)d_in[4];
    float* out = (float*)d_out;

    unsigned short* wk = (unsigned short*)d_ws;                       // [B][H][R][C] bf16
    unsigned short* wv = wk + (size_t)Bdim*Hdim*Rdim*Cdim;            // [B][H][C][R] bf16

    proj_kernel<<<dim3(512), 256, 0, stream>>>(k, v, pk, pv, wk, wv);
    attn_kernel<<<dim3(Ldim/64, Bdim*Hdim), 256, 0, stream>>>(q, wk, wv, out);
}